// Round 1
// baseline (43.005 us; speedup 1.0000x reference)
//
#include <hip/hip_runtime.h>

// Problem constants (from reference):
//   X_train: [1024, 128] f32; coalition_vectors: [64, 128] f32 (0/1); instance: [8, 128] f32
//   out0 = filled_X [1, M*C*N + M, 128] = [1, 524296, 128]
//   out1 = instance [8, 128]
//   d_out = out0 flat ++ out1 flat = 67,110,912 floats (~268 MB)

#define N_TRAIN 1024
#define D_FEAT  128
#define N_COAL  64
#define N_INST  8

constexpr int ROWS_MAIN  = N_INST * N_COAL * N_TRAIN;   // 524288 rows of where-select
constexpr int ROWS_TOTAL = ROWS_MAIN + 2 * N_INST;      // + 8 (concat tail) + 8 (out1) = 524304
constexpr int Q_PER_ROW  = D_FEAT / 4;                  // 32 float4 per row
constexpr int TOTAL_Q    = ROWS_TOTAL * Q_PER_ROW;      // 16,777,728 float4 stores

__global__ void shap_fill_kernel(const float4* __restrict__ X4,     // [1024*32]
                                 const float4* __restrict__ coal4,  // [64*32]
                                 const float4* __restrict__ inst4,  // [8*32]
                                 float4* __restrict__ out4) {
    int i = blockIdx.x * blockDim.x + threadIdx.x;
    if (i >= TOTAL_Q) return;

    const int row = i >> 5;      // / Q_PER_ROW
    const int q   = i & 31;      // float4 index within the 128-float row

    float4 v;
    if (row < ROWS_MAIN) {
        // row = m*65536 + c*1024 + n  (all pow2 -> bit ops)
        const int n = row & (N_TRAIN - 1);
        const int c = (row >> 10) & (N_COAL - 1);
        const int m = row >> 16;

        const float4 mk = coal4[c * Q_PER_ROW + q];
        const float4 iv = inst4[m * Q_PER_ROW + q];
        const float4 xv = X4[n * Q_PER_ROW + q];

        v.x = (mk.x != 0.0f) ? iv.x : xv.x;
        v.y = (mk.y != 0.0f) ? iv.y : xv.y;
        v.z = (mk.z != 0.0f) ? iv.z : xv.z;
        v.w = (mk.w != 0.0f) ? iv.w : xv.w;
    } else {
        // Tail: rows [524288,524296) = instance appended to filled_X;
        //       rows [524296,524304) = output 1 (instance again). Both are instance copies.
        const int m = (row - ROWS_MAIN) & (N_INST - 1);
        v = inst4[m * Q_PER_ROW + q];
    }
    out4[i] = v;
}

extern "C" void kernel_launch(void* const* d_in, const int* in_sizes, int n_in,
                              void* d_out, int out_size, void* d_ws, size_t ws_size,
                              hipStream_t stream) {
    const float4* X4     = (const float4*)d_in[0];  // X_train
    const float4* coal4  = (const float4*)d_in[1];  // coalition_vectors
    const float4* inst4  = (const float4*)d_in[2];  // instance
    float4* out4 = (float4*)d_out;

    const int threads = 256;
    const int blocks  = (TOTAL_Q + threads - 1) / threads;  // 65538
    shap_fill_kernel<<<blocks, threads, 0, stream>>>(X4, coal4, inst4, out4);
}